// Round 6
// baseline (188.960 us; speedup 1.0000x reference)
//
#include <hip/hip_runtime.h>
#include <math.h>

#define BB 2
#define KK 8
#define NB 256            // histogram bins over error in [0,2]
#define HALF_NB_F 128.0f
#define FAR_CUT 5.5452f   // ln(256): s*sq above this => bin 0 (non-label)

#define PXB_H 1024
#define GRID_H 2048       // BB*NPB/PXB_H (1024 per b)
#define PXB_A 4096
#define GRID_A 512        // 256 per b
#define NPART_A 256

#define STEP_T (0.1f/31.0f)
#define STEP_Y (1.6f/799.0f)
#define STEP_X (4.16f/1999.0f)

// ws float-offset layout
#define OFF_ACC 0        // 96: seg*6 (only count used downstream)
#define OFF_PRM 100      // 96: seg*6 + {ct, cy, cx, s_exp, var_k, present}
#define CNT0 240
#define CNT1 241
#define OFF_GH2 512      // u64 seg-hist [16][256] -> floats 512..8704
#define OFF_PARTA 9216   // k_acc partials [b][f][256] = 24576 floats
#define OFF_SEED2 34816  // k_hist seed partials float2[2048]
#define OFF_HIST_F 40960 // partial hists u32 [2048][KK*NB] = 16 MB

// ---------------- pass 1: per-(b,k) sums in registers + plain-store partials ----------------
__global__ __launch_bounds__(256) void k_acc(const float* __restrict__ pred,
                                             const int* __restrict__ inst,
                                             float* __restrict__ ws) {
  int tid = threadIdx.x, blk = blockIdx.x;
  int b = blk >> 8;
  int rbase = (blk & 255) * PXB_A;
  const float* sig_p = pred + ((size_t)b * 5 << 20) + (3 << 20);
  const int* ip = inst + ((size_t)b << 20);
  float acc[48];
  #pragma unroll
  for (int f = 0; f < 48; ++f) acc[f] = 0.f;
  for (int it = 0; it < 4; ++it) {
    int r = rbase + it * 1024 + 4 * tid;
    float4 sg4 = *(const float4*)(sig_p + r);
    int4 id4 = *(const int4*)(ip + r);
    float tf = (float)(r >> 17), hf = (float)((r >> 9) & 255), wf = (float)(r & 511);
    float sv[4] = {sg4.x, sg4.y, sg4.z, sg4.w};
    int iv[4] = {id4.x, id4.y, id4.z, id4.w};
    #pragma unroll
    for (int j = 0; j < 4; ++j) {
      #pragma unroll
      for (int k = 0; k < KK; ++k) {
        float m = (iv[j] == k + 1) ? 1.f : 0.f;
        acc[k*6+0] += m;
        acc[k*6+1] += m * sv[j];
        acc[k*6+2] += m * sv[j] * sv[j];
        acc[k*6+3] += m * tf;
        acc[k*6+4] += m * hf;
        acc[k*6+5] += m * (wf + (float)j);
      }
    }
  }
  __shared__ float lds[4 * 48];
  __shared__ float accs[96];
  __shared__ int lastA;
  int lane = tid & 63, wv = tid >> 6;
  #pragma unroll
  for (int f = 0; f < 48; ++f) {
    float v = acc[f];
    for (int o = 32; o; o >>= 1) v += __shfl_down(v, o);
    if (lane == 0) lds[wv * 48 + f] = v;
  }
  __syncthreads();
  if (tid < 48)
    ws[OFF_PARTA + ((size_t)b * 48 + tid) * NPART_A + (blk & 255)]
      = lds[tid] + lds[48 + tid] + lds[96 + tid] + lds[144 + tid];
  __threadfence();
  __syncthreads();
  if (tid == 0) lastA = (atomicAdd((unsigned*)ws + CNT0, 1u) == GRID_A - 1) ? 1 : 0;
  __syncthreads();
  if (!lastA) return;
  __threadfence();
  if (tid < 96) {
    const float* p = ws + OFF_PARTA + (size_t)tid * NPART_A;
    float s = 0.f;
    for (int j = 0; j < NPART_A; ++j) s += p[j];
    accs[tid] = s;
  }
  __syncthreads();
  if (tid < 16) {
    float* a = &accs[(tid >> 3) * 48 + (tid & 7) * 6];
    float cnt = a[0], s1 = a[1], s2 = a[2], st = a[3], sy = a[4], sx = a[5];
    float safe = fmaxf(cnt, 1.f);
    float smean = s1 / safe;
    ws[OFF_ACC + tid*6 + 0] = cnt;
    ws[OFF_PRM + tid*6 + 0] = st * STEP_T / safe;
    ws[OFF_PRM + tid*6 + 1] = sy * STEP_Y / safe;
    ws[OFF_PRM + tid*6 + 2] = sx * STEP_X / safe;
    ws[OFF_PRM + tid*6 + 3] = __expf(10.f * smean);
    ws[OFF_PRM + tid*6 + 4] = s2 / safe - smean * smean;
    ws[OFF_PRM + tid*6 + 5] = (cnt > 0.f) ? 1.f : 0.f;
  }
}

__device__ __forceinline__ float fast_tanh(float x) {
  x = fminf(fmaxf(x, -15.f), 15.f);
  float ex = __expf(2.f * x);
  return (ex - 1.f) / (ex + 1.f);
}

// ---------------- pass 2: LDS-private histogram, 4 px/thread, plain-store flush ----------------
__global__ __launch_bounds__(256, 8) void k_hist(const float* __restrict__ pred,
                                                 const int* __restrict__ inst,
                                                 float* __restrict__ ws) {
  __shared__ unsigned int hist[KK * NB];  // packed: neg low16, pos high16
  __shared__ float Ps[KK * 4];
  __shared__ unsigned int pmask_s;
  __shared__ float wred[8];
  int tid = threadIdx.x;
  int blk = blockIdx.x;
  int b = blk >> 10;
  for (int i = tid; i < KK * NB; i += 256) hist[i] = 0u;
  if (tid < KK) {
    int seg = b * 8 + tid;
    Ps[tid*4+0] = ws[OFF_PRM + seg*6 + 0];
    Ps[tid*4+1] = ws[OFF_PRM + seg*6 + 1];
    Ps[tid*4+2] = ws[OFF_PRM + seg*6 + 2];
    Ps[tid*4+3] = ws[OFF_PRM + seg*6 + 3];
  }
  if (tid == 0) {
    unsigned m = 0;
    for (int k = 0; k < KK; ++k)
      if (ws[OFF_PRM + (b*8+k)*6 + 5] > 0.f) m |= 1u << k;
    pmask_s = m;
  }
  __syncthreads();
  unsigned pmask = pmask_s;
  int r = (blk & 1023) * PXB_H + 4 * tid;
  const float* pb = pred + ((size_t)b * 5 << 20);
  float tf = (float)(r >> 17), hf = (float)((r >> 9) & 255);
  int w = r & 511;
  float4 p0 = *(const float4*)(pb + r);
  float4 p1 = *(const float4*)(pb + (1 << 20) + r);
  float4 p2 = *(const float4*)(pb + (2 << 20) + r);
  float4 p4 = *(const float4*)(pb + (4 << 20) + r);
  int4 id4 = *(const int4*)(inst + ((size_t)b << 20) + r);
  int iv[4] = {id4.x, id4.y, id4.z, id4.w};
  float e0[4], e1[4], e2[4], sd[4];
  {
    float q0[4] = {p0.x,p0.y,p0.z,p0.w}, q1[4] = {p1.x,p1.y,p1.z,p1.w};
    float q2[4] = {p2.x,p2.y,p2.z,p2.w}, q4[4] = {p4.x,p4.y,p4.z,p4.w};
    #pragma unroll
    for (int j = 0; j < 4; ++j) {
      e0[j] = fast_tanh(q0[j]) + tf * STEP_T;
      e1[j] = fast_tanh(q1[j]) + hf * STEP_Y;
      e2[j] = fast_tanh(q2[j]) + (float)(w + j) * STEP_X;
      sd[j] = 1.f / (1.f + __expf(-q4[j]));
    }
  }
  float sbg = 0.f, sfg = 0.f;
  #pragma unroll
  for (int j = 0; j < 4; ++j) if (iv[j] == 0) sbg += sd[j] * sd[j];
  int lane = tid & 63;
  #pragma unroll
  for (int k = 0; k < KK; ++k) {
    if (!((pmask >> k) & 1)) continue;   // block-uniform
    float4 P = *(float4*)&Ps[k * 4];     // LDS broadcast
    float ssq[4];
    bool lab[4], any_need = false;
    #pragma unroll
    for (int j = 0; j < 4; ++j) {
      float dt = e0[j] - P.x, dy = e1[j] - P.y, dx = e2[j] - P.z;
      ssq[j] = P.w * (dt*dt + dy*dy + dx*dx);
      lab[j] = (iv[j] == k + 1);
      any_need |= (ssq[j] < FAR_CUT) | lab[j];
    }
    if (__any(any_need)) {
      unsigned long long mlo[4], mto[4], mla[4];
      int bin[4]; bool low[4], top[4];
      #pragma unroll
      for (int j = 0; j < 4; ++j) {
        float d = __expf(-ssq[j]);
        if (lab[j]) { float df = sd[j] - d; sfg += df * df; }
        float e = lab[j] ? (2.f - 2.f * d) : (2.f * d);
        bin[j] = min((int)(e * HALF_NB_F), NB - 1);
        low[j] = (bin[j] == 0); top[j] = (bin[j] == NB - 1);
        mla[j] = __ballot(lab[j]); mlo[j] = __ballot(low[j]); mto[j] = __ballot(top[j]);
      }
      if (lane == 0) {
        unsigned vlow = 0, vtop = 0;
        #pragma unroll
        for (int j = 0; j < 4; ++j) {
          vlow += (unsigned)__popcll(mlo[j] & ~mla[j]) + ((unsigned)__popcll(mlo[j] & mla[j]) << 16);
          vtop += (unsigned)__popcll(mto[j] & ~mla[j]) + ((unsigned)__popcll(mto[j] & mla[j]) << 16);
        }
        if (vlow) atomicAdd(&hist[k * NB], vlow);
        if (vtop) atomicAdd(&hist[k * NB + NB - 1], vtop);
      }
      #pragma unroll
      for (int j = 0; j < 4; ++j)
        if (!low[j] && !top[j]) atomicAdd(&hist[k * NB + bin[j]], lab[j] ? 0x10000u : 1u);
    } else {
      if (lane == 0) atomicAdd(&hist[k * NB], 256u);  // 4 px * 64 lanes, bin0 neg
    }
  }
  for (int off = 32; off; off >>= 1) {
    sbg += __shfl_down(sbg, off);
    sfg += __shfl_down(sfg, off);
  }
  if (lane == 0) { wred[(tid >> 6) * 2] = sbg; wred[(tid >> 6) * 2 + 1] = sfg; }
  __syncthreads();
  if (tid == 0)
    ((float2*)(ws + OFF_SEED2))[blk] =
      make_float2(wred[0] + wred[2] + wred[4] + wred[6],
                  wred[1] + wred[3] + wred[5] + wred[7]);
  // plain coalesced uint4 flush of this block's private histogram
  uint4* gp = (uint4*)((unsigned int*)(ws + OFF_HIST_F) + (size_t)blk * (KK * NB));
  const uint4* hs = (const uint4*)hist;
  #pragma unroll
  for (int i = 0; i < 2; ++i) gp[i * 256 + tid] = hs[i * 256 + tid];
}

// ---------------- pass 3: tree-reduce partials + Lovasz scan + final ----------------
__global__ __launch_bounds__(256) void k_lovasz(float* __restrict__ ws, float* __restrict__ out) {
  int blk = blockIdx.x;               // 256 blocks: seg = blk>>4, bin-range = blk&15
  int tid = threadIdx.x;
  int seg = blk >> 4, range = blk & 15;
  int b = seg >> 3, k = seg & 7;
  __shared__ unsigned long long sred[256];
  __shared__ int lastL;
  __shared__ double segtot[16];
  __shared__ float sdb[4], sdf[4];
  // phase 1: sum 1024 partial histograms over this seg's 16-bin range
  {
    int bin_off = tid & 15;
    int pgrp = tid >> 4;              // 16 groups, each sums 64 partials
    const unsigned int* gh = (const unsigned int*)(ws + OFF_HIST_F);
    size_t base = ((size_t)b * 1024 + (size_t)pgrp * 64) * (KK * NB)
                + (size_t)k * NB + (size_t)range * 16 + bin_off;
    unsigned int neg = 0, pos = 0;
    #pragma unroll 4
    for (int j = 0; j < 64; ++j) {
      unsigned v = gh[base + (size_t)j * (KK * NB)];
      neg += v & 0xFFFFu; pos += v >> 16;
    }
    sred[tid] = ((unsigned long long)pos << 32) | neg;
  }
  __syncthreads();
  if (tid < 16) {
    unsigned long long a = 0;
    #pragma unroll
    for (int j = 0; j < 16; ++j) a += sred[tid + j * 16];
    if (a) atomicAdd((unsigned long long*)(ws + OFF_GH2) + seg * NB + range * 16 + tid, a);
  }
  __syncthreads();
  if (tid == 0) {
    __threadfence();
    lastL = (atomicAdd((unsigned*)ws + CNT1, 1u) == 255) ? 1 : 0;
  }
  __syncthreads();
  if (!lastL) return;
  if (tid == 0) __threadfence();
  __syncthreads();
  int lane = tid & 63, wv = tid >> 6;
  // seed-partial reduction: 2048 float2; waves 0-1 -> b0, waves 2-3 -> b1
  {
    const float2* sp = (const float2*)(ws + OFF_SEED2);
    float sb = 0.f, sf = 0.f;
    #pragma unroll
    for (int j = 0; j < 8; ++j) { float2 v = sp[tid * 8 + j]; sb += v.x; sf += v.y; }
    for (int o = 32; o; o >>= 1) { sb += __shfl_down(sb, o); sf += __shfl_down(sf, o); }
    if (lane == 0) { sdb[wv] = sb; sdf[wv] = sf; }
  }
  // Lovasz scans: 4 waves x 4 segs
  unsigned long long* gh2 = (unsigned long long*)(ws + OFF_GH2);
  for (int s = wv; s < 16; s += 4) {
    double total = 0.0;
    if (ws[OFF_PRM + s*6 + 5] != 0.f) {
      double gts = (double)ws[OFF_ACC + s*6 + 0];
      unsigned long long carry = 0;
      double sum = 0.0;
      for (int c = 0; c < NB / 64; ++c) {
        int bin = NB - 1 - (c * 64 + lane);   // descending-error order
        unsigned long long v = atomicAdd(&gh2[s * NB + bin], 0ull);
        unsigned long long orig = v;
        #pragma unroll
        for (int o = 1; o < 64; o <<= 1) {
          unsigned long long u = (unsigned long long)__shfl_up((long long)v, o, 64);
          if (lane >= o) v += u;
        }
        v += carry;
        if (orig) {
          unsigned int ip = (unsigned)(v >> 32), in_ = (unsigned)v;
          unsigned int ppx = (unsigned)(orig >> 32), nnx = (unsigned)orig;
          double ep = (double)(ip - ppx), en = (double)(in_ - nnx);
          double js = 1.0 - (gts - ep) / (gts + en);
          double je = 1.0 - (gts - (double)ip) / (gts + (double)in_);
          sum += ((double)bin + 0.5) * (2.0 / NB) * (je - js);
        }
        carry = (unsigned long long)__shfl((long long)v, 63, 64);
      }
      for (int o = 32; o; o >>= 1) sum += __shfl_down(sum, o);
      total = sum;
    }
    if (lane == 0) segtot[s] = total;
  }
  __syncthreads();
  if (tid == 0) {
    double tot = 0.0;
    for (int bb = 0; bb < BB; ++bb) {
      double il = 0.0, vl = 0.0, ob = 0.0;
      for (int k2 = 0; k2 < KK; ++k2) {
        int s2 = bb * 8 + k2;
        double pr = (double)ws[OFF_PRM + s2*6 + 5];
        il += segtot[s2] * pr;
        vl += (double)ws[OFF_PRM + s2*6 + 4] * pr;
        ob += pr;
      }
      double so = (ob > 1.0) ? ob : 1.0;
      double sbg = (double)sdb[bb * 2] + (double)sdb[bb * 2 + 1];
      double sfg = (double)sdf[bb * 2] + (double)sdf[bb * 2 + 1];
      tot += il / so + 10.0 * vl / so + (sbg + sfg) / (256.0 * 512.0);
    }
    out[0] = (float)(tot / BB);
  }
}

extern "C" void kernel_launch(void* const* d_in, const int* in_sizes, int n_in,
                              void* d_out, int out_size, void* d_ws, size_t ws_size,
                              hipStream_t stream) {
  const float* pred = (const float*)d_in[0];
  const int* inst = (const int*)d_in[1];
  float* ws = (float*)d_ws;
  float* out = (float*)d_out;
  // zero: ACC/PRM/counters + seg-hist. Partials/seed/hist regions fully overwritten.
  hipMemsetAsync(d_ws, 0, 8704 * sizeof(float), stream);
  k_acc<<<GRID_A, 256, 0, stream>>>(pred, inst, ws);
  k_hist<<<GRID_H, 256, 0, stream>>>(pred, inst, ws);
  k_lovasz<<<256, 256, 0, stream>>>(ws, out);
}

// Round 7
// 145.314 us; speedup vs baseline: 1.3004x; 1.3004x over previous
//
#include <hip/hip_runtime.h>
#include <math.h>

#define BB 2
#define KK 8
#define NB 256            // histogram bins over error in [0,2]
#define HALF_NB_F 128.0f
#define FAR_CUT 5.5452f   // ln(256): s*sq above this => bin 0 (non-label)

#define PXB_H 1024
#define GRID_H 2048       // BB*NPB/PXB_H (1024 per b)
#define PXB_A 4096
#define GRID_A 512        // 256 per b
#define NPART_A 256

#define STEP_T (0.1f/31.0f)
#define STEP_Y (1.6f/799.0f)
#define STEP_X (4.16f/1999.0f)

// ws float-offset layout
#define OFF_ACC 0        // 96: seg*6 (only count used downstream)
#define OFF_PRM 100      // 96: seg*6 + {ct, cy, cx, s_exp, var_k, present}
#define OFF_GH2 512      // u64 seg-hist [16][256] -> floats 512..8704
#define OFF_PARTA 9216   // k_acc partials [b*48+f][256] = 24576 floats
#define OFF_SEED2 34816  // k_hist seed partials float2[2048]
#define OFF_HIST_F 40960 // partial hists u32 [2048][KK*NB] = 16 MB

// ---------------- pass 1: per-(b,k) sums in registers, plain-store partials ----------------
__global__ __launch_bounds__(256) void k_acc(const float* __restrict__ pred,
                                             const int* __restrict__ inst,
                                             float* __restrict__ ws) {
  int tid = threadIdx.x, blk = blockIdx.x;
  int b = blk >> 8;
  int rbase = (blk & 255) * PXB_A;
  const float* sig_p = pred + ((size_t)b * 5 << 20) + (3 << 20);
  const int* ip = inst + ((size_t)b << 20);
  float acc[48];
  #pragma unroll
  for (int f = 0; f < 48; ++f) acc[f] = 0.f;
  for (int it = 0; it < 4; ++it) {
    int r = rbase + it * 1024 + 4 * tid;
    float4 sg4 = *(const float4*)(sig_p + r);
    int4 id4 = *(const int4*)(ip + r);
    float tf = (float)(r >> 17), hf = (float)((r >> 9) & 255), wf = (float)(r & 511);
    float sv[4] = {sg4.x, sg4.y, sg4.z, sg4.w};
    int iv[4] = {id4.x, id4.y, id4.z, id4.w};
    #pragma unroll
    for (int j = 0; j < 4; ++j) {
      #pragma unroll
      for (int k = 0; k < KK; ++k) {
        float m = (iv[j] == k + 1) ? 1.f : 0.f;
        acc[k*6+0] += m;
        acc[k*6+1] += m * sv[j];
        acc[k*6+2] += m * sv[j] * sv[j];
        acc[k*6+3] += m * tf;
        acc[k*6+4] += m * hf;
        acc[k*6+5] += m * (wf + (float)j);
      }
    }
  }
  __shared__ float lds[4 * 48];
  int lane = tid & 63, wv = tid >> 6;
  #pragma unroll
  for (int f = 0; f < 48; ++f) {
    float v = acc[f];
    for (int o = 32; o; o >>= 1) v += __shfl_down(v, o);
    if (lane == 0) lds[wv * 48 + f] = v;
  }
  __syncthreads();
  if (tid < 48)
    ws[OFF_PARTA + ((size_t)b * 48 + tid) * NPART_A + (blk & 255)]
      = lds[tid] + lds[48 + tid] + lds[96 + tid] + lds[144 + tid];
}

// ---------------- pass 1b: reduce partials, derive params (1 block) ----------------
__global__ __launch_bounds__(256) void k_params(float* __restrict__ ws) {
  __shared__ float accs[96];
  int tid = threadIdx.x;
  if (tid < 96) {
    const float* p = ws + OFF_PARTA + (size_t)tid * NPART_A;
    float s0 = 0.f, s1 = 0.f, s2 = 0.f, s3 = 0.f;
    for (int j = 0; j < NPART_A; j += 4) {
      s0 += p[j]; s1 += p[j+1]; s2 += p[j+2]; s3 += p[j+3];
    }
    accs[tid] = (s0 + s1) + (s2 + s3);
  }
  __syncthreads();
  if (tid < 16) {
    float* a = &accs[(tid >> 3) * 48 + (tid & 7) * 6];
    float cnt = a[0], s1 = a[1], s2 = a[2], st = a[3], sy = a[4], sx = a[5];
    float safe = fmaxf(cnt, 1.f);
    float smean = s1 / safe;
    ws[OFF_ACC + tid*6 + 0] = cnt;
    ws[OFF_PRM + tid*6 + 0] = st * STEP_T / safe;
    ws[OFF_PRM + tid*6 + 1] = sy * STEP_Y / safe;
    ws[OFF_PRM + tid*6 + 2] = sx * STEP_X / safe;
    ws[OFF_PRM + tid*6 + 3] = __expf(10.f * smean);
    ws[OFF_PRM + tid*6 + 4] = s2 / safe - smean * smean;
    ws[OFF_PRM + tid*6 + 5] = (cnt > 0.f) ? 1.f : 0.f;
  }
}

__device__ __forceinline__ float fast_tanh(float x) {
  x = fminf(fmaxf(x, -15.f), 15.f);
  float ex = __expf(2.f * x);
  return (ex - 1.f) / (ex + 1.f);
}

// ---------------- pass 2: LDS-private histogram, 4 px/thread, plain-store flush ----------------
__global__ __launch_bounds__(256, 8) void k_hist(const float* __restrict__ pred,
                                                 const int* __restrict__ inst,
                                                 float* __restrict__ ws) {
  __shared__ unsigned int hist[KK * NB];  // packed: neg low16, pos high16
  __shared__ float Ps[KK * 4];
  __shared__ unsigned int pmask_s;
  __shared__ float wred[8];
  int tid = threadIdx.x;
  int blk = blockIdx.x;
  int b = blk >> 10;
  for (int i = tid; i < KK * NB; i += 256) hist[i] = 0u;
  if (tid < KK) {
    int seg = b * 8 + tid;
    Ps[tid*4+0] = ws[OFF_PRM + seg*6 + 0];
    Ps[tid*4+1] = ws[OFF_PRM + seg*6 + 1];
    Ps[tid*4+2] = ws[OFF_PRM + seg*6 + 2];
    Ps[tid*4+3] = ws[OFF_PRM + seg*6 + 3];
  }
  if (tid == 0) {
    unsigned m = 0;
    for (int k = 0; k < KK; ++k)
      if (ws[OFF_PRM + (b*8+k)*6 + 5] > 0.f) m |= 1u << k;
    pmask_s = m;
  }
  __syncthreads();
  unsigned pmask = pmask_s;
  int r = (blk & 1023) * PXB_H + 4 * tid;
  const float* pb = pred + ((size_t)b * 5 << 20);
  float tf = (float)(r >> 17), hf = (float)((r >> 9) & 255);
  int w = r & 511;
  float4 p0 = *(const float4*)(pb + r);
  float4 p1 = *(const float4*)(pb + (1 << 20) + r);
  float4 p2 = *(const float4*)(pb + (2 << 20) + r);
  float4 p4 = *(const float4*)(pb + (4 << 20) + r);
  int4 id4 = *(const int4*)(inst + ((size_t)b << 20) + r);
  int iv[4] = {id4.x, id4.y, id4.z, id4.w};
  float e0[4], e1[4], e2[4], sd[4];
  {
    float q0[4] = {p0.x,p0.y,p0.z,p0.w}, q1[4] = {p1.x,p1.y,p1.z,p1.w};
    float q2[4] = {p2.x,p2.y,p2.z,p2.w}, q4[4] = {p4.x,p4.y,p4.z,p4.w};
    #pragma unroll
    for (int j = 0; j < 4; ++j) {
      e0[j] = fast_tanh(q0[j]) + tf * STEP_T;
      e1[j] = fast_tanh(q1[j]) + hf * STEP_Y;
      e2[j] = fast_tanh(q2[j]) + (float)(w + j) * STEP_X;
      sd[j] = 1.f / (1.f + __expf(-q4[j]));
    }
  }
  float sbg = 0.f, sfg = 0.f;
  #pragma unroll
  for (int j = 0; j < 4; ++j) if (iv[j] == 0) sbg += sd[j] * sd[j];
  int lane = tid & 63;
  #pragma unroll
  for (int k = 0; k < KK; ++k) {
    if (!((pmask >> k) & 1)) continue;   // block-uniform
    float4 P = *(float4*)&Ps[k * 4];     // LDS broadcast
    float ssq[4];
    bool lab[4], any_need = false;
    #pragma unroll
    for (int j = 0; j < 4; ++j) {
      float dt = e0[j] - P.x, dy = e1[j] - P.y, dx = e2[j] - P.z;
      ssq[j] = P.w * (dt*dt + dy*dy + dx*dx);
      lab[j] = (iv[j] == k + 1);
      any_need |= (ssq[j] < FAR_CUT) | lab[j];
    }
    if (__any(any_need)) {
      unsigned long long mlo[4], mto[4], mla[4];
      int bin[4]; bool low[4], top[4];
      #pragma unroll
      for (int j = 0; j < 4; ++j) {
        float d = __expf(-ssq[j]);
        if (lab[j]) { float df = sd[j] - d; sfg += df * df; }
        float e = lab[j] ? (2.f - 2.f * d) : (2.f * d);
        bin[j] = min((int)(e * HALF_NB_F), NB - 1);
        low[j] = (bin[j] == 0); top[j] = (bin[j] == NB - 1);
        mla[j] = __ballot(lab[j]); mlo[j] = __ballot(low[j]); mto[j] = __ballot(top[j]);
      }
      if (lane == 0) {
        unsigned vlow = 0, vtop = 0;
        #pragma unroll
        for (int j = 0; j < 4; ++j) {
          vlow += (unsigned)__popcll(mlo[j] & ~mla[j]) + ((unsigned)__popcll(mlo[j] & mla[j]) << 16);
          vtop += (unsigned)__popcll(mto[j] & ~mla[j]) + ((unsigned)__popcll(mto[j] & mla[j]) << 16);
        }
        if (vlow) atomicAdd(&hist[k * NB], vlow);
        if (vtop) atomicAdd(&hist[k * NB + NB - 1], vtop);
      }
      #pragma unroll
      for (int j = 0; j < 4; ++j)
        if (!low[j] && !top[j]) atomicAdd(&hist[k * NB + bin[j]], lab[j] ? 0x10000u : 1u);
    } else {
      if (lane == 0) atomicAdd(&hist[k * NB], 256u);  // 4 px * 64 lanes, bin0 neg
    }
  }
  for (int off = 32; off; off >>= 1) {
    sbg += __shfl_down(sbg, off);
    sfg += __shfl_down(sfg, off);
  }
  if (lane == 0) { wred[(tid >> 6) * 2] = sbg; wred[(tid >> 6) * 2 + 1] = sfg; }
  __syncthreads();
  if (tid == 0)
    ((float2*)(ws + OFF_SEED2))[blk] =
      make_float2(wred[0] + wred[2] + wred[4] + wred[6],
                  wred[1] + wred[3] + wred[5] + wred[7]);
  // plain coalesced uint4 flush of this block's private histogram
  uint4* gp = (uint4*)((unsigned int*)(ws + OFF_HIST_F) + (size_t)blk * (KK * NB));
  const uint4* hs = (const uint4*)hist;
  #pragma unroll
  for (int i = 0; i < 2; ++i) gp[i * 256 + tid] = hs[i * 256 + tid];
}

// ---------------- pass 3a: reduce partial hists -> seg-hist (exclusive, plain stores) ----------------
__global__ __launch_bounds__(256) void k_red(float* __restrict__ ws) {
  int blk = blockIdx.x;               // 256 blocks: seg = blk>>4, bin-range = blk&15
  int tid = threadIdx.x;
  int seg = blk >> 4, range = blk & 15;
  int b = seg >> 3, k = seg & 7;
  __shared__ unsigned long long sred[256];
  int bin_off = tid & 15;
  int pgrp = tid >> 4;                // 16 groups, each sums 64 partials
  const unsigned int* gh = (const unsigned int*)(ws + OFF_HIST_F);
  size_t base = ((size_t)b * 1024 + (size_t)pgrp * 64) * (KK * NB)
              + (size_t)k * NB + (size_t)range * 16 + bin_off;
  unsigned int neg = 0, pos = 0;
  #pragma unroll 4
  for (int j = 0; j < 64; ++j) {
    unsigned v = gh[base + (size_t)j * (KK * NB)];
    neg += v & 0xFFFFu; pos += v >> 16;
  }
  sred[tid] = ((unsigned long long)pos << 32) | neg;
  __syncthreads();
  if (tid < 16) {
    unsigned long long a = 0;
    #pragma unroll
    for (int j = 0; j < 16; ++j) a += sred[tid + j * 16];
    ((unsigned long long*)(ws + OFF_GH2))[seg * NB + range * 16 + tid] = a;
  }
}

// ---------------- pass 3b: seed reduce + Lovasz scans + final (1 block) ----------------
__global__ __launch_bounds__(256) void k_fin(float* __restrict__ ws, float* __restrict__ out) {
  int tid = threadIdx.x;
  int lane = tid & 63, wv = tid >> 6;
  __shared__ double segtot[16];
  __shared__ float sdb[4], sdf[4];
  // seed-partial reduction: 2048 float2; waves 0-1 -> b0, waves 2-3 -> b1
  {
    const float2* sp = (const float2*)(ws + OFF_SEED2);
    float sb = 0.f, sf = 0.f;
    #pragma unroll
    for (int j = 0; j < 8; ++j) { float2 v = sp[tid * 8 + j]; sb += v.x; sf += v.y; }
    for (int o = 32; o; o >>= 1) { sb += __shfl_down(sb, o); sf += __shfl_down(sf, o); }
    if (lane == 0) { sdb[wv] = sb; sdf[wv] = sf; }
  }
  // Lovasz scans: 4 waves x 4 segs
  const unsigned long long* gh2 = (const unsigned long long*)(ws + OFF_GH2);
  for (int s = wv; s < 16; s += 4) {
    double total = 0.0;
    if (ws[OFF_PRM + s*6 + 5] != 0.f) {
      double gts = (double)ws[OFF_ACC + s*6 + 0];
      unsigned long long carry = 0;
      double sum = 0.0;
      for (int c = 0; c < NB / 64; ++c) {
        int bin = NB - 1 - (c * 64 + lane);   // descending-error order
        unsigned long long v = gh2[s * NB + bin];
        unsigned long long orig = v;
        #pragma unroll
        for (int o = 1; o < 64; o <<= 1) {
          unsigned long long u = (unsigned long long)__shfl_up((long long)v, o, 64);
          if (lane >= o) v += u;
        }
        v += carry;
        if (orig) {
          unsigned int ip = (unsigned)(v >> 32), in_ = (unsigned)v;
          unsigned int ppx = (unsigned)(orig >> 32), nnx = (unsigned)orig;
          double ep = (double)(ip - ppx), en = (double)(in_ - nnx);
          double js = 1.0 - (gts - ep) / (gts + en);
          double je = 1.0 - (gts - (double)ip) / (gts + (double)in_);
          sum += ((double)bin + 0.5) * (2.0 / NB) * (je - js);
        }
        carry = (unsigned long long)__shfl((long long)v, 63, 64);
      }
      for (int o = 32; o; o >>= 1) sum += __shfl_down(sum, o);
      total = sum;
    }
    if (lane == 0) segtot[s] = total;
  }
  __syncthreads();
  if (tid == 0) {
    double tot = 0.0;
    for (int bb = 0; bb < BB; ++bb) {
      double il = 0.0, vl = 0.0, ob = 0.0;
      for (int k2 = 0; k2 < KK; ++k2) {
        int s2 = bb * 8 + k2;
        double pr = (double)ws[OFF_PRM + s2*6 + 5];
        il += segtot[s2] * pr;
        vl += (double)ws[OFF_PRM + s2*6 + 4] * pr;
        ob += pr;
      }
      double so = (ob > 1.0) ? ob : 1.0;
      double sbg = (double)sdb[bb * 2] + (double)sdb[bb * 2 + 1];
      double sfg = (double)sdf[bb * 2] + (double)sdf[bb * 2 + 1];
      tot += il / so + 10.0 * vl / so + (sbg + sfg) / (256.0 * 512.0);
    }
    out[0] = (float)(tot / BB);
  }
}

extern "C" void kernel_launch(void* const* d_in, const int* in_sizes, int n_in,
                              void* d_out, int out_size, void* d_ws, size_t ws_size,
                              hipStream_t stream) {
  const float* pred = (const float*)d_in[0];
  const int* inst = (const int*)d_in[1];
  float* ws = (float*)d_ws;
  float* out = (float*)d_out;
  // No memset needed: every ws region consumed downstream is fully written by
  // its producer kernel; kernel boundaries provide device-wide visibility.
  k_acc<<<GRID_A, 256, 0, stream>>>(pred, inst, ws);
  k_params<<<1, 256, 0, stream>>>(ws);
  k_hist<<<GRID_H, 256, 0, stream>>>(pred, inst, ws);
  k_red<<<256, 256, 0, stream>>>(ws);
  k_fin<<<1, 256, 0, stream>>>(ws, out);
}